// Round 4
// baseline (155.448 us; speedup 1.0000x reference)
//
#include <hip/hip_runtime.h>
#include <math.h>

#define NN 50000
#define FD 128
#define HDIM 256
#define NE 800000
#define NBR_CAP 512
#define M_CAP 8192
#define TT 7
#define DBLK 8          // tail kernel blocks
#define DTHR 1024       // tail kernel threads/block

// ws byte offsets
#define O_DEG      0         // NN floats (zeroed by k_nbr, not memset)
#define O_BITMAP   200704    // 1568 words
#define O_NBRCNT   207104
#define O_MCNT     207232
#define O_BAR      207360    // barrier counter (zeroed each call by memset)
#define O_NBRNODE  207616    // NBR_CAP ints
#define O_NBRW     209664    // NBR_CAP floats
#define O_MS       211712    // M_CAP ints
#define O_MD       244480    // M_CAP ints
#define O_MW       277248    // M_CAP floats
#define O_A1X      310016    // 128 f
#define O_A2X      310528    // 128 f
#define O_A1H      311040    // 256 f
#define O_A2H      312064    // 256 f
#define O_GACC     313088    // 4*256 f
#define O_HBUF     317184    // 2*256 f
#define O_OBUF     319232    // TT f
#define WS_END     319264
#define CTRL_OFF   O_BITMAP
#define CTRL_BYTES (WS_END - O_BITMAP)

__device__ __forceinline__ float sigm(float v) { return 1.f / (1.f + expf(-v)); }
__device__ __forceinline__ float dis_of(float dg) {
    return dg > 0.f ? rsqrtf(fmaxf(dg, 1e-20f)) : 0.f;
}

// 8-arrival device barrier. ACQUIRE spin (guaranteed visibility) with s_sleep(4)
// backoff (~170ns) so the invalidate traffic from 8 spinners stays negligible.
__device__ __forceinline__ void gbar8(unsigned* bar) {
    __syncthreads();
    if (threadIdx.x == 0) {
        unsigned old = __hip_atomic_fetch_add(bar, 1u, __ATOMIC_ACQ_REL, __HIP_MEMORY_SCOPE_AGENT);
        unsigned tgt = (old / DBLK + 1u) * DBLK;
        while (__hip_atomic_load(bar, __ATOMIC_ACQUIRE, __HIP_MEMORY_SCOPE_AGENT) < tgt)
            __builtin_amdgcn_s_sleep(4);
    }
    __syncthreads();
}

// Scan 1: collect in-neighbors of node 0; also zero deg (replaces big memset).
__global__ void k_nbr(const int* __restrict__ ei, const float* __restrict__ ew,
                      float* deg, int* nbrCnt, int* nbrNode, float* nbrW) {
    int gid = blockIdx.x * blockDim.x + threadIdx.x;
    if (gid < NN) deg[gid] = 0.f;
    int e0 = gid * 4;
    if (e0 >= NE) return;
    int4 d4 = *(const int4*)&ei[NE + e0];
    float4 w4 = *(const float4*)&ew[e0];
    int dd[4] = {d4.x, d4.y, d4.z, d4.w};
    float wv[4] = {w4.x, w4.y, w4.z, w4.w};
    #pragma unroll
    for (int k = 0; k < 4; ++k) {
        if (dd[k] == 0 && wv[k] != 0.f) {
            int s = ei[e0 + k];
            if (s != 0) {
                int slot = atomicAdd(nbrCnt, 1);
                if (slot < NBR_CAP) { nbrNode[slot] = s; nbrW[slot] = wv[k]; }
            }
        }
    }
}

// Scan 2: match edges with d==0 or d in nbr(0); record (s,d,w); mark needed nodes.
__global__ void k_match(const int* __restrict__ ei, const float* __restrict__ ew,
                        const int* __restrict__ nbrCnt, const int* __restrict__ nbrNode,
                        int* mCnt, int* mS, int* mD, float* mW, unsigned* bitmap) {
    __shared__ int sNode[NBR_CAP];
    __shared__ int sCnt;
    if (threadIdx.x == 0) sCnt = min(*nbrCnt, NBR_CAP);
    __syncthreads();
    int cnt = sCnt;
    for (int i = threadIdx.x; i < cnt; i += blockDim.x) sNode[i] = nbrNode[i];
    __syncthreads();
    if (blockIdx.x == 0 && threadIdx.x == 0) atomicOr(&bitmap[0], 1u);

    int i = blockIdx.x * blockDim.x + threadIdx.x;
    int e0 = i * 4;
    if (e0 >= NE) return;
    int4 s4 = *(const int4*)&ei[e0];
    int4 d4 = *(const int4*)&ei[NE + e0];
    float4 w4 = *(const float4*)&ew[e0];
    int ss[4] = {s4.x, s4.y, s4.z, s4.w};
    int dd[4] = {d4.x, d4.y, d4.z, d4.w};
    float wv[4] = {w4.x, w4.y, w4.z, w4.w};
    bool m[4];
    #pragma unroll
    for (int k = 0; k < 4; ++k) m[k] = (dd[k] == 0);
    for (int j = 0; j < cnt; ++j) {
        int nv = sNode[j];
        #pragma unroll
        for (int k = 0; k < 4; ++k) m[k] |= (dd[k] == nv);
    }
    #pragma unroll
    for (int k = 0; k < 4; ++k) {
        int s = ss[k], d = dd[k];
        float w = wv[k];
        if (s == d || w == 0.f || !m[k]) continue;
        int slot = atomicAdd(mCnt, 1);
        if (slot < M_CAP) { mS[slot] = s; mD[slot] = d; mW[slot] = w; }
        atomicOr(&bitmap[s >> 5], 1u << (s & 31));
        atomicOr(&bitmap[d >> 5], 1u << (d & 31));
    }
}

// Scan 3: deg[s] += w only for bitmap-marked srcs.
__global__ void k_deg(const int* __restrict__ ei, const float* __restrict__ ew,
                      const unsigned* __restrict__ bitmap, float* deg) {
    int i = blockIdx.x * blockDim.x + threadIdx.x;
    int e0 = i * 4;
    if (e0 >= NE) return;
    int4 s4 = *(const int4*)&ei[e0];
    int4 d4 = *(const int4*)&ei[NE + e0];
    float4 w4 = *(const float4*)&ew[e0];
    int ss[4] = {s4.x, s4.y, s4.z, s4.w};
    int dd[4] = {d4.x, d4.y, d4.z, d4.w};
    float wv[4] = {w4.x, w4.y, w4.z, w4.w};
    #pragma unroll
    for (int k = 0; k < 4; ++k) {
        int s = ss[k];
        if (s == dd[k] || wv[k] == 0.f) continue;
        if (bitmap[s >> 5] & (1u << (s & 31)))
            atomicAdd(&deg[s], wv[k]);
    }
}

// Tail: accum -> gemv -> gates -> 7 LSTM steps -> out. 8 blocks x 1024 threads.
// Block b owns 128 gate rows {strip*256 + b*32 + k} held in VGPRs (32 f/thread),
// and h-outputs o in [b*32, b*32+32).
__global__ __launch_bounds__(DTHR) void k_tail(
    const float* __restrict__ x, const float* __restrict__ h, const float* __restrict__ c,
    const float* __restrict__ theta_x, const float* __restrict__ bias_x,
    const float* __restrict__ theta_h, const float* __restrict__ bias_h,
    const float* __restrict__ w_c, const float* __restrict__ b_gate,
    const float* __restrict__ w_ih, const float* __restrict__ w_hh,
    const float* __restrict__ b_ih, const float* __restrict__ b_hh,
    const float* __restrict__ w_out, const float* __restrict__ b_out,
    float* __restrict__ out, char* __restrict__ ws) {

    float*    deg    = (float*)(ws + O_DEG);
    int*      nbrCnt = (int*)(ws + O_NBRCNT);
    int*      mCnt   = (int*)(ws + O_MCNT);
    unsigned* bar    = (unsigned*)(ws + O_BAR);
    int*      nbrNode= (int*)(ws + O_NBRNODE);
    float*    nbrW   = (float*)(ws + O_NBRW);
    int*      mS     = (int*)(ws + O_MS);
    int*      mD     = (int*)(ws + O_MD);
    float*    mW     = (float*)(ws + O_MW);
    float*    A1x    = (float*)(ws + O_A1X);
    float*    A2x    = (float*)(ws + O_A2X);
    float*    A1h    = (float*)(ws + O_A1H);
    float*    A2h    = (float*)(ws + O_A2H);
    float*    gacc   = (float*)(ws + O_GACC);
    float*    hbuf   = (float*)(ws + O_HBUF);
    float*    obuf   = (float*)(ws + O_OBUF);

    __shared__ int   sNode[NBR_CAP];
    __shared__ float sWl[NBR_CAP];
    __shared__ float tx[3 * FD];
    __shared__ float th[3 * HDIM];
    __shared__ float sh[HDIM];
    __shared__ float sc[HDIM];
    __shared__ float sdot[128];
    __shared__ float sinp_s;
    __shared__ int   sCnt, sMcnt;

    const int tid = threadIdx.x, bid = blockIdx.x;

    // ---- preload this thread's w_hh row-chunk into VGPRs (32 floats) ----
    const int rl = tid >> 3, part = tid & 7;                    // rl in [0,128)
    const int grow = (rl >> 5) * HDIM + bid * 32 + (rl & 31);   // global gate row
    float4 wreg[8];
    #pragma unroll
    for (int k = 0; k < 8; ++k)
        wreg[k] = *(const float4*)&w_hh[(size_t)grow * HDIM + part * 32 + k * 4];
    const float wih_r = w_ih[grow];
    const float br    = b_ih[grow] + b_hh[grow];
    const float bo    = b_out[0];
    const float wout_r = (tid < 32) ? w_out[bid * 32 + tid] : 0.f;

    if (tid == 0) { sCnt = min(*nbrCnt, NBR_CAP); sMcnt = min(*mCnt, M_CAP); }
    __syncthreads();
    const int ncnt = sCnt, mcnt = sMcnt;
    for (int i = tid; i < ncnt; i += DTHR) { sNode[i] = nbrNode[i]; sWl[i] = nbrW[i]; }
    __syncthreads();

    // ---- accum: A1/A2 over matched edges ----
    if (tid < 384) {
        const float dis0 = dis_of(deg[0]);
        float a1 = 0.f, a2 = 0.f;
        for (int i = bid; i < mcnt; i += DBLK) {
            int s = mS[i], d = mD[i];
            float w = mW[i];
            float diss = dis_of(deg[s]);
            float disd = dis_of(deg[d]);
            float wn = diss * w * disd;
            float c1 = (d == 0) ? wn : 0.f;
            float Wd = 0.f;
            for (int j = 0; j < ncnt; ++j) Wd += (sNode[j] == d) ? sWl[j] : 0.f;
            float c2 = wn * (dis0 * disd * Wd);
            float v = (tid < FD) ? x[(size_t)s * FD + tid] : h[(size_t)s * HDIM + (tid - FD)];
            a1 += c1 * v;
            a2 += c2 * v;
        }
        if (tid < FD) { atomicAdd(&A1x[tid], a1); atomicAdd(&A2x[tid], a2); }
        else          { atomicAdd(&A1h[tid - FD], a1); atomicAdd(&A2h[tid - FD], a2); }
    }
    gbar8(bar);                          // B1: A1/A2 complete

    // ---- gemv: gacc[g][o] += sum_p T[p]*theta[g][p][o] ----
    for (int i = tid; i < FD; i += DTHR) {
        float x0 = x[i];
        tx[i] = x0;
        tx[FD + i] = -A1x[i];                    // T1 = -A1
        tx[2 * FD + i] = 2.f * A2x[i] - x0;      // T2 = 2*lhat(T1) - T0
    }
    for (int i = tid; i < HDIM; i += DTHR) {
        float h0 = h[i];
        th[i] = h0;
        th[HDIM + i] = -A1h[i];
        th[2 * HDIM + i] = 2.f * A2h[i] - h0;
    }
    __syncthreads();
    {
        const int g = bid >> 1, hf = bid & 1, sub = tid >> 8, o = tid & 255;
        const int PX = 3 * FD, CH = 144;         // 1152/8
        const int p0 = (hf * 4 + sub) * CH;
        float acc = 0.f;
        for (int p = p0; p < p0 + CH; ++p) {
            float tval;
            const float* row;
            if (p < PX) { tval = tx[p]; row = theta_x + (size_t)(g * PX + p) * HDIM; }
            else { int q = p - PX; tval = th[q]; row = theta_h + (size_t)(g * 3 * HDIM + q) * HDIM; }
            acc += tval * row[o];
        }
        atomicAdd(&gacc[g * HDIM + o], acc);
    }
    gbar8(bar);                          // B2: gacc complete

    // ---- gates: every block computes full h0 (redundant), c0 kept per-block ----
    if (tid < HDIM) {
        int o = tid;
        float g0 = gacc[0 * HDIM + o] + bias_x[0 * HDIM + o] + bias_h[0 * HDIM + o];
        float g1 = gacc[1 * HDIM + o] + bias_x[1 * HDIM + o] + bias_h[1 * HDIM + o];
        float g2 = gacc[2 * HDIM + o] + bias_x[2 * HDIM + o] + bias_h[2 * HDIM + o];
        float g3 = gacc[3 * HDIM + o] + bias_x[3 * HDIM + o] + bias_h[3 * HDIM + o];
        float c0 = c[o];
        float I  = sigm(g0 + w_c[0 * HDIM + o] * c0 + b_gate[0 * HDIM + o]);
        float Fg = sigm(g1 + w_c[1 * HDIM + o] * c0 + b_gate[1 * HDIM + o]);
        float Cn = Fg * c0 + I * tanhf(g2 + b_gate[2 * HDIM + o]);
        float O  = sigm(g3 + w_c[2 * HDIM + o] * Cn + b_gate[3 * HDIM + o]);
        sh[o] = O * tanhf(Cn);
        sc[o] = Cn;
    }
    float creg = 0.f;

    // ---- 7 LSTM steps ----
    for (int t = 0; t < TT; ++t) {
        if (tid == 0) sinp_s = (t == 0) ? x[FD - 1] : (obuf[t - 1] + bo);
        __syncthreads();                 // sh, sc, sinp_s visible
        const float sinp = sinp_s;
        float acc = 0.f;
        #pragma unroll
        for (int k = 0; k < 8; ++k) {
            float4 hv = *(const float4*)&sh[part * 32 + k * 4];
            acc += hv.x * wreg[k].x + hv.y * wreg[k].y + hv.z * wreg[k].z + hv.w * wreg[k].w;
        }
        acc += __shfl_down(acc, 4);
        acc += __shfl_down(acc, 2);
        acc += __shfl_down(acc, 1);
        if (part == 0) sdot[rl] = acc + sinp * wih_r + br;
        __syncthreads();
        if (tid < 64) {
            float hn_v = 0.f;
            if (tid < 32) {
                if (t == 0) creg = sc[bid * 32 + tid];
                float iv = sdot[tid], fv = sdot[32 + tid], gv = sdot[64 + tid], ov = sdot[96 + tid];
                float cn = sigm(fv) * creg + sigm(iv) * tanhf(gv);
                float hn = sigm(ov) * tanhf(cn);
                creg = cn;
                __hip_atomic_store(&hbuf[((t + 1) & 1) * HDIM + bid * 32 + tid], hn,
                                   __ATOMIC_RELAXED, __HIP_MEMORY_SCOPE_AGENT);
                hn_v = hn;
            }
            float po = hn_v * wout_r;
            po += __shfl_down(po, 16);
            po += __shfl_down(po, 8);
            po += __shfl_down(po, 4);
            po += __shfl_down(po, 2);
            po += __shfl_down(po, 1);
            if (tid == 0) atomicAdd(&obuf[t], po);
        }
        gbar8(bar);                      // all h parts + obuf[t] complete
        if (tid < 64)
            *(float4*)&sh[tid * 4] = *(const float4*)&hbuf[((t + 1) & 1) * HDIM + tid * 4];
        // next iteration's initial __syncthreads orders this write before use
    }

    if (bid == 0 && tid < TT) out[tid] = obuf[tid] + bo;
}

extern "C" void kernel_launch(void* const* d_in, const int* in_sizes, int n_in,
                              void* d_out, int out_size, void* d_ws, size_t ws_size,
                              hipStream_t stream) {
    const float* x       = (const float*)d_in[0];
    const int*   ei      = (const int*)d_in[1];
    const float* ew      = (const float*)d_in[2];
    const float* h       = (const float*)d_in[3];
    const float* c       = (const float*)d_in[4];
    const float* theta_x = (const float*)d_in[5];
    const float* bias_x  = (const float*)d_in[6];
    const float* theta_h = (const float*)d_in[7];
    const float* bias_h  = (const float*)d_in[8];
    const float* w_c     = (const float*)d_in[9];
    const float* b_gate  = (const float*)d_in[10];
    const float* w_ih    = (const float*)d_in[11];
    const float* w_hh    = (const float*)d_in[12];
    const float* b_ih    = (const float*)d_in[13];
    const float* b_hh    = (const float*)d_in[14];
    const float* w_out   = (const float*)d_in[15];
    const float* b_out   = (const float*)d_in[16];
    char* ws = (char*)d_ws;

    float*    deg    = (float*)(ws + O_DEG);
    unsigned* bitmap = (unsigned*)(ws + O_BITMAP);
    int*      nbrCnt = (int*)(ws + O_NBRCNT);
    int*      mCnt   = (int*)(ws + O_MCNT);
    int*      nbrNode= (int*)(ws + O_NBRNODE);
    float*    nbrW   = (float*)(ws + O_NBRW);
    int*      mS     = (int*)(ws + O_MS);
    int*      mD     = (int*)(ws + O_MD);
    float*    mW     = (float*)(ws + O_MW);

    hipMemsetAsync(ws + CTRL_OFF, 0, CTRL_BYTES, stream);

    int eb4 = (NE / 4 + 255) / 256;
    k_nbr<<<eb4, 256, 0, stream>>>(ei, ew, deg, nbrCnt, nbrNode, nbrW);
    k_match<<<eb4, 256, 0, stream>>>(ei, ew, nbrCnt, nbrNode, mCnt, mS, mD, mW, bitmap);
    k_deg<<<eb4, 256, 0, stream>>>(ei, ew, bitmap, deg);
    k_tail<<<DBLK, DTHR, 0, stream>>>(x, h, c, theta_x, bias_x, theta_h, bias_h,
                                      w_c, b_gate, w_ih, w_hh, b_ih, b_hh, w_out, b_out,
                                      (float*)d_out, ws);
}

// Round 5
// 85.702 us; speedup vs baseline: 1.8138x; 1.8138x over previous
//
#include <hip/hip_runtime.h>
#include <math.h>

#define NN 50000
#define FD 128
#define HDIM 256
#define NE 800000
#define NBR_CAP 512
#define M_CAP 8192
#define TT 7
#define TAILB 32        // tail blocks
#define TTHR 256        // tail threads/block

// ws byte offsets
#define O_DEG      0         // NN floats (zeroed by k_nbr)
#define O_BITMAP   200704    // 1568 words
#define O_NBRCNT   207104
#define O_MCNT     207232
#define O_BAR      207360
#define O_A1X      207616    // 128 f
#define O_A2X      208128    // 128 f
#define O_A1H      208640    // 256 f
#define O_A2H      209664    // 256 f
#define O_GACC     210688    // 1024 f
#define O_OBUF     214784    // TT f
#define O_HBUF     214912    // 2*256 f
#define O_CTRL_END 216960
#define CTRL_OFF   O_BITMAP
#define CTRL_BYTES (O_CTRL_END - O_BITMAP)
#define O_NBRNODE  216960    // NBR_CAP ints
#define O_NBRW     219008    // NBR_CAP floats
#define O_MS       221056    // M_CAP ints
#define O_MD       253824    // M_CAP ints
#define O_MW       286592    // M_CAP floats

__device__ __forceinline__ float sigm(float v) { return 1.f / (1.f + expf(-v)); }
__device__ __forceinline__ float dis_of(float dg) {
    return dg > 0.f ? rsqrtf(fmaxf(dg, 1e-20f)) : 0.f;
}

// Device barrier. Arrival AND poll are atomic RMWs: RMWs execute at the
// memory-side coherent point (LLC) and are never served from the stale
// per-XCD L2 (the round-3/4 failure mode of plain-load polling).
__device__ __forceinline__ void gbar(unsigned* bar) {
    __syncthreads();
    if (threadIdx.x == 0) {
        unsigned old = __hip_atomic_fetch_add(bar, 1u, __ATOMIC_ACQ_REL, __HIP_MEMORY_SCOPE_AGENT);
        unsigned tgt = (old / TAILB + 1u) * TAILB;
        while (__hip_atomic_fetch_add(bar, 0u, __ATOMIC_ACQUIRE, __HIP_MEMORY_SCOPE_AGENT) < tgt)
            __builtin_amdgcn_s_sleep(2);
    }
    __syncthreads();
}

__device__ __forceinline__ float aload(const float* p) {
    return __hip_atomic_load(p, __ATOMIC_RELAXED, __HIP_MEMORY_SCOPE_AGENT);
}
__device__ __forceinline__ void astore(float* p, float v) {
    __hip_atomic_store(p, v, __ATOMIC_RELAXED, __HIP_MEMORY_SCOPE_AGENT);
}

// Scan 1: collect in-neighbors of node 0; zero deg.
__global__ void k_nbr(const int* __restrict__ ei, const float* __restrict__ ew,
                      float* deg, int* nbrCnt, int* nbrNode, float* nbrW) {
    int gid = blockIdx.x * blockDim.x + threadIdx.x;
    if (gid < NN) deg[gid] = 0.f;
    int e0 = gid * 4;
    if (e0 >= NE) return;
    int4 d4 = *(const int4*)&ei[NE + e0];
    float4 w4 = *(const float4*)&ew[e0];
    int dd[4] = {d4.x, d4.y, d4.z, d4.w};
    float wv[4] = {w4.x, w4.y, w4.z, w4.w};
    #pragma unroll
    for (int k = 0; k < 4; ++k) {
        if (dd[k] == 0 && wv[k] != 0.f) {
            int s = ei[e0 + k];
            if (s != 0) {
                int slot = atomicAdd(nbrCnt, 1);
                if (slot < NBR_CAP) { nbrNode[slot] = s; nbrW[slot] = wv[k]; }
            }
        }
    }
}

// Scan 2: match edges with d==0 or d in nbr(0); record (s,d,w); mark needed nodes.
__global__ void k_match(const int* __restrict__ ei, const float* __restrict__ ew,
                        const int* __restrict__ nbrCnt, const int* __restrict__ nbrNode,
                        int* mCnt, int* mS, int* mD, float* mW, unsigned* bitmap) {
    __shared__ int sNode[NBR_CAP];
    __shared__ int sCnt;
    if (threadIdx.x == 0) sCnt = min(*nbrCnt, NBR_CAP);
    __syncthreads();
    int cnt = sCnt;
    for (int i = threadIdx.x; i < cnt; i += blockDim.x) sNode[i] = nbrNode[i];
    __syncthreads();
    if (blockIdx.x == 0 && threadIdx.x == 0) atomicOr(&bitmap[0], 1u);

    int i = blockIdx.x * blockDim.x + threadIdx.x;
    int e0 = i * 4;
    if (e0 >= NE) return;
    int4 s4 = *(const int4*)&ei[e0];
    int4 d4 = *(const int4*)&ei[NE + e0];
    float4 w4 = *(const float4*)&ew[e0];
    int ss[4] = {s4.x, s4.y, s4.z, s4.w};
    int dd[4] = {d4.x, d4.y, d4.z, d4.w};
    float wv[4] = {w4.x, w4.y, w4.z, w4.w};
    bool m[4];
    #pragma unroll
    for (int k = 0; k < 4; ++k) m[k] = (dd[k] == 0);
    for (int j = 0; j < cnt; ++j) {
        int nv = sNode[j];
        #pragma unroll
        for (int k = 0; k < 4; ++k) m[k] |= (dd[k] == nv);
    }
    #pragma unroll
    for (int k = 0; k < 4; ++k) {
        int s = ss[k], d = dd[k];
        float w = wv[k];
        if (s == d || w == 0.f || !m[k]) continue;
        int slot = atomicAdd(mCnt, 1);
        if (slot < M_CAP) { mS[slot] = s; mD[slot] = d; mW[slot] = w; }
        atomicOr(&bitmap[s >> 5], 1u << (s & 31));
        atomicOr(&bitmap[d >> 5], 1u << (d & 31));
    }
}

// Scan 3: deg[s] += w only for bitmap-marked srcs.
__global__ void k_deg(const int* __restrict__ ei, const float* __restrict__ ew,
                      const unsigned* __restrict__ bitmap, float* deg) {
    int i = blockIdx.x * blockDim.x + threadIdx.x;
    int e0 = i * 4;
    if (e0 >= NE) return;
    int4 s4 = *(const int4*)&ei[e0];
    int4 d4 = *(const int4*)&ei[NE + e0];
    float4 w4 = *(const float4*)&ew[e0];
    int ss[4] = {s4.x, s4.y, s4.z, s4.w};
    int dd[4] = {d4.x, d4.y, d4.z, d4.w};
    float wv[4] = {w4.x, w4.y, w4.z, w4.w};
    #pragma unroll
    for (int k = 0; k < 4; ++k) {
        int s = ss[k];
        if (s == dd[k] || wv[k] == 0.f) continue;
        if (bitmap[s >> 5] & (1u << (s & 31)))
            atomicAdd(&deg[s], wv[k]);
    }
}

// Tail: accum -> gemv -> gates -> 7 LSTM steps. 32 blocks x 256 threads.
// Block b owns gate rows {g*256 + b*8 + k} (w_hh held in VGPRs, 32 f/thread)
// and h-outputs [b*8, b*8+8).
__global__ __launch_bounds__(TTHR) void k_tail(
    const float* __restrict__ x, const float* __restrict__ h, const float* __restrict__ c,
    const float* __restrict__ theta_x, const float* __restrict__ bias_x,
    const float* __restrict__ theta_h, const float* __restrict__ bias_h,
    const float* __restrict__ w_c, const float* __restrict__ b_gate,
    const float* __restrict__ w_ih, const float* __restrict__ w_hh,
    const float* __restrict__ b_ih, const float* __restrict__ b_hh,
    const float* __restrict__ w_out, const float* __restrict__ b_out,
    float* __restrict__ out, char* __restrict__ ws) {

    float*    deg    = (float*)(ws + O_DEG);
    int*      nbrCnt = (int*)(ws + O_NBRCNT);
    int*      mCnt   = (int*)(ws + O_MCNT);
    unsigned* bar    = (unsigned*)(ws + O_BAR);
    int*      nbrNode= (int*)(ws + O_NBRNODE);
    float*    nbrW   = (float*)(ws + O_NBRW);
    int*      mS     = (int*)(ws + O_MS);
    int*      mD     = (int*)(ws + O_MD);
    float*    mW     = (float*)(ws + O_MW);
    float*    A1x    = (float*)(ws + O_A1X);
    float*    A2x    = (float*)(ws + O_A2X);
    float*    A1h    = (float*)(ws + O_A1H);
    float*    A2h    = (float*)(ws + O_A2H);
    float*    gacc   = (float*)(ws + O_GACC);
    float*    hbuf   = (float*)(ws + O_HBUF);
    float*    obuf   = (float*)(ws + O_OBUF);

    __shared__ int   sNode[NBR_CAP];
    __shared__ float sWl[NBR_CAP];
    __shared__ float tx[3 * FD];
    __shared__ float th[3 * HDIM];
    __shared__ float sh[HDIM];
    __shared__ float sc[HDIM];
    __shared__ float sdot[32];
    __shared__ float sinp_s;
    __shared__ int   sCnt, sMcnt;

    const int tid = threadIdx.x, bid = blockIdx.x;

    // ---- preload this thread's w_hh row-chunk into VGPRs (32 floats) ----
    const int rl = tid >> 3, seg = tid & 7;                     // rl: 32 rows/block
    const int grow = (rl >> 3) * HDIM + bid * 8 + (rl & 7);     // gate*256 + b*8 + oo
    float4 wreg[8];
    #pragma unroll
    for (int k = 0; k < 8; ++k)
        wreg[k] = *(const float4*)&w_hh[(size_t)grow * HDIM + seg * 32 + k * 4];
    const float wih_r = w_ih[grow];
    const float br    = b_ih[grow] + b_hh[grow];
    const float bo    = b_out[0];
    const float wout_r = (tid < 8) ? w_out[bid * 8 + tid] : 0.f;

    if (tid == 0) { sCnt = min(*nbrCnt, NBR_CAP); sMcnt = min(*mCnt, M_CAP); }
    __syncthreads();
    const int ncnt = sCnt, mcnt = sMcnt;
    for (int i = tid; i < ncnt; i += TTHR) { sNode[i] = nbrNode[i]; sWl[i] = nbrW[i]; }
    __syncthreads();

    // ---- accum: A1/A2 over matched edges (distributed across blocks) ----
    {
        const float dis0 = dis_of(deg[0]);
        float a1x = 0.f, a2x = 0.f, a1h = 0.f, a2h = 0.f;
        for (int i = bid; i < mcnt; i += TAILB) {
            int s = mS[i], d = mD[i];
            float w = mW[i];
            float disd = dis_of(deg[d]);
            float wn = dis_of(deg[s]) * w * disd;
            float c1 = (d == 0) ? wn : 0.f;
            float Wd = 0.f;
            for (int j = 0; j < ncnt; ++j) Wd += (sNode[j] == d) ? sWl[j] : 0.f;
            float c2 = wn * (dis0 * disd * Wd);
            float vh = h[(size_t)s * HDIM + tid];
            a1h += c1 * vh; a2h += c2 * vh;
            if (tid < FD) {
                float vx = x[(size_t)s * FD + tid];
                a1x += c1 * vx; a2x += c2 * vx;
            }
        }
        atomicAdd(&A1h[tid], a1h); atomicAdd(&A2h[tid], a2h);
        if (tid < FD) { atomicAdd(&A1x[tid], a1x); atomicAdd(&A2x[tid], a2x); }
    }
    gbar(bar);                           // B0: A1/A2 complete

    // ---- build T vectors (A written by atomics -> never locally cached: plain loads OK)
    if (tid < FD) {
        float x0 = x[tid];
        tx[tid] = x0;
        tx[FD + tid] = -A1x[tid];                 // T1 = -A1
        tx[2 * FD + tid] = 2.f * A2x[tid] - x0;   // T2 = 2*lhat(T1) - T0
    }
    {
        float h0 = h[tid];
        th[tid] = h0;
        th[HDIM + tid] = -A1h[tid];
        th[2 * HDIM + tid] = 2.f * A2h[tid] - h0;
    }
    __syncthreads();

    // ---- gemv: block owns p-slice [bid*36, bid*36+36); thread: oq=tid&63, pseg=tid>>6
    {
        const int oq = tid & 63, pseg = tid >> 6;
        const int p0 = bid * 36 + pseg * 9;
        float4 a0 = {0,0,0,0}, a1 = {0,0,0,0}, a2 = {0,0,0,0}, a3 = {0,0,0,0};
        #pragma unroll
        for (int pp = 0; pp < 9; ++pp) {
            int p = p0 + pp;
            bool isx = p < 3 * FD;
            int q = isx ? p : p - 3 * FD;
            float tv = isx ? tx[p] : th[q];
            const float* b0 = isx ? theta_x + ((size_t)(0 * 384 + q)) * HDIM
                                  : theta_h + ((size_t)(0 * 768 + q)) * HDIM;
            const float* b1 = isx ? theta_x + ((size_t)(1 * 384 + q)) * HDIM
                                  : theta_h + ((size_t)(1 * 768 + q)) * HDIM;
            const float* b2 = isx ? theta_x + ((size_t)(2 * 384 + q)) * HDIM
                                  : theta_h + ((size_t)(2 * 768 + q)) * HDIM;
            const float* b3 = isx ? theta_x + ((size_t)(3 * 384 + q)) * HDIM
                                  : theta_h + ((size_t)(3 * 768 + q)) * HDIM;
            float4 v0 = *(const float4*)&b0[oq * 4];
            float4 v1 = *(const float4*)&b1[oq * 4];
            float4 v2 = *(const float4*)&b2[oq * 4];
            float4 v3 = *(const float4*)&b3[oq * 4];
            a0.x += tv * v0.x; a0.y += tv * v0.y; a0.z += tv * v0.z; a0.w += tv * v0.w;
            a1.x += tv * v1.x; a1.y += tv * v1.y; a1.z += tv * v1.z; a1.w += tv * v1.w;
            a2.x += tv * v2.x; a2.y += tv * v2.y; a2.z += tv * v2.z; a2.w += tv * v2.w;
            a3.x += tv * v3.x; a3.y += tv * v3.y; a3.z += tv * v3.z; a3.w += tv * v3.w;
        }
        int ob = oq * 4;
        atomicAdd(&gacc[0 * HDIM + ob + 0], a0.x); atomicAdd(&gacc[0 * HDIM + ob + 1], a0.y);
        atomicAdd(&gacc[0 * HDIM + ob + 2], a0.z); atomicAdd(&gacc[0 * HDIM + ob + 3], a0.w);
        atomicAdd(&gacc[1 * HDIM + ob + 0], a1.x); atomicAdd(&gacc[1 * HDIM + ob + 1], a1.y);
        atomicAdd(&gacc[1 * HDIM + ob + 2], a1.z); atomicAdd(&gacc[1 * HDIM + ob + 3], a1.w);
        atomicAdd(&gacc[2 * HDIM + ob + 0], a2.x); atomicAdd(&gacc[2 * HDIM + ob + 1], a2.y);
        atomicAdd(&gacc[2 * HDIM + ob + 2], a2.z); atomicAdd(&gacc[2 * HDIM + ob + 3], a2.w);
        atomicAdd(&gacc[3 * HDIM + ob + 0], a3.x); atomicAdd(&gacc[3 * HDIM + ob + 1], a3.y);
        atomicAdd(&gacc[3 * HDIM + ob + 2], a3.z); atomicAdd(&gacc[3 * HDIM + ob + 3], a3.w);
    }
    gbar(bar);                           // B1: gacc complete

    // ---- gates: every block redundantly computes full h0/c0 into LDS ----
    {
        int o = tid;
        float g0 = gacc[0 * HDIM + o] + bias_x[0 * HDIM + o] + bias_h[0 * HDIM + o];
        float g1 = gacc[1 * HDIM + o] + bias_x[1 * HDIM + o] + bias_h[1 * HDIM + o];
        float g2 = gacc[2 * HDIM + o] + bias_x[2 * HDIM + o] + bias_h[2 * HDIM + o];
        float g3 = gacc[3 * HDIM + o] + bias_x[3 * HDIM + o] + bias_h[3 * HDIM + o];
        float c0 = c[o];
        float I  = sigm(g0 + w_c[0 * HDIM + o] * c0 + b_gate[0 * HDIM + o]);
        float Fg = sigm(g1 + w_c[1 * HDIM + o] * c0 + b_gate[1 * HDIM + o]);
        float Cn = Fg * c0 + I * tanhf(g2 + b_gate[2 * HDIM + o]);
        float O  = sigm(g3 + w_c[2 * HDIM + o] * Cn + b_gate[3 * HDIM + o]);
        sh[o] = O * tanhf(Cn);
        sc[o] = Cn;
    }
    float creg = 0.f;

    // ---- 7 LSTM steps ----
    for (int t = 0; t < TT; ++t) {
        if (tid == 0) sinp_s = (t == 0) ? x[FD - 1] : (aload(&obuf[t - 1]) + bo);
        __syncthreads();                 // sh, sc, sinp_s visible
        const float sinp = sinp_s;
        float acc = 0.f;
        #pragma unroll
        for (int k = 0; k < 8; ++k) {
            float4 hv = *(const float4*)&sh[seg * 32 + k * 4];
            acc += hv.x * wreg[k].x + hv.y * wreg[k].y + hv.z * wreg[k].z + hv.w * wreg[k].w;
        }
        acc += __shfl_down(acc, 4);
        acc += __shfl_down(acc, 2);
        acc += __shfl_down(acc, 1);
        if (seg == 0) sdot[rl] = acc + sinp * wih_r + br;
        __syncthreads();
        if (tid < 8) {
            if (t == 0) creg = sc[bid * 8 + tid];
            float iv = sdot[tid], fv = sdot[8 + tid], gv = sdot[16 + tid], ov = sdot[24 + tid];
            float cn = sigm(fv) * creg + sigm(iv) * tanhf(gv);
            float hn = sigm(ov) * tanhf(cn);
            creg = cn;
            astore(&hbuf[((t + 1) & 1) * HDIM + bid * 8 + tid], hn);
            float po = hn * wout_r;
            po += __shfl_down(po, 4);
            po += __shfl_down(po, 2);
            po += __shfl_down(po, 1);
            if (tid == 0) atomicAdd(&obuf[t], po);
        }
        gbar(bar);                       // all h parts + obuf[t] complete
        sh[tid] = aload(&hbuf[((t + 1) & 1) * HDIM + tid]);
        // next iteration's leading __syncthreads orders this write before use
    }

    if (bid == 0 && tid < TT) out[tid] = aload(&obuf[tid]) + bo;
}

extern "C" void kernel_launch(void* const* d_in, const int* in_sizes, int n_in,
                              void* d_out, int out_size, void* d_ws, size_t ws_size,
                              hipStream_t stream) {
    const float* x       = (const float*)d_in[0];
    const int*   ei      = (const int*)d_in[1];
    const float* ew      = (const float*)d_in[2];
    const float* h       = (const float*)d_in[3];
    const float* c       = (const float*)d_in[4];
    const float* theta_x = (const float*)d_in[5];
    const float* bias_x  = (const float*)d_in[6];
    const float* theta_h = (const float*)d_in[7];
    const float* bias_h  = (const float*)d_in[8];
    const float* w_c     = (const float*)d_in[9];
    const float* b_gate  = (const float*)d_in[10];
    const float* w_ih    = (const float*)d_in[11];
    const float* w_hh    = (const float*)d_in[12];
    const float* b_ih    = (const float*)d_in[13];
    const float* b_hh    = (const float*)d_in[14];
    const float* w_out   = (const float*)d_in[15];
    const float* b_out   = (const float*)d_in[16];
    char* ws = (char*)d_ws;

    float*    deg    = (float*)(ws + O_DEG);
    unsigned* bitmap = (unsigned*)(ws + O_BITMAP);
    int*      nbrCnt = (int*)(ws + O_NBRCNT);
    int*      mCnt   = (int*)(ws + O_MCNT);
    int*      nbrNode= (int*)(ws + O_NBRNODE);
    float*    nbrW   = (float*)(ws + O_NBRW);
    int*      mS     = (int*)(ws + O_MS);
    int*      mD     = (int*)(ws + O_MD);
    float*    mW     = (float*)(ws + O_MW);

    hipMemsetAsync(ws + CTRL_OFF, 0, CTRL_BYTES, stream);

    int eb4 = (NE / 4 + 255) / 256;
    k_nbr<<<eb4, 256, 0, stream>>>(ei, ew, deg, nbrCnt, nbrNode, nbrW);
    k_match<<<eb4, 256, 0, stream>>>(ei, ew, nbrCnt, nbrNode, mCnt, mS, mD, mW, bitmap);
    k_deg<<<eb4, 256, 0, stream>>>(ei, ew, bitmap, deg);
    k_tail<<<TAILB, TTHR, 0, stream>>>(x, h, c, theta_x, bias_x, theta_h, bias_h,
                                       w_c, b_gate, w_ih, w_hh, b_ih, b_hh, w_out, b_out,
                                       (float*)d_out, ws);
}

// Round 6
// 68.136 us; speedup vs baseline: 2.2814x; 1.2578x over previous
//
#include <hip/hip_runtime.h>
#include <math.h>

#define NN 50000
#define FD 128
#define HDIM 256
#define NE 800000
#define NBR_CAP 512
#define M_CAP 8192
#define TT 7
#define TAILB 32
#define TTHR 256
#define ECHUNK 2048
#define PSLICE 36            // 1152 p-values / 32 blocks

// ws byte offsets
#define O_DEG      0         // NN floats (zeroed by k_nbr)
#define O_BITMAP   200704    // 1568 words -> ends 206976
#define O_NBRCNT   206976
#define O_MCNT     206980
#define O_DONE     206984
#define O_FLAGS    207104    // TT*32 u32 = 896 -> 208000
#define O_GACC     208000    // 1024 f -> 212096
#define O_HGLOB    212096    // TT*256 f -> 219264
#define O_CTRL_END 219264
#define CTRL_OFF   O_BITMAP
#define CTRL_BYTES (O_CTRL_END - O_BITMAP)
#define O_NBRNODE  219264    // NBR_CAP ints
#define O_NBRW     221312    // NBR_CAP floats
#define O_MS       223360    // M_CAP ints
#define O_MD       256128    // M_CAP ints
#define O_MW       288896    // M_CAP floats -> 321664

__device__ __forceinline__ float sigm(float v) { return 1.f / (1.f + expf(-v)); }
__device__ __forceinline__ float dis_of(float dg) {
    return dg > 0.f ? rsqrtf(fmaxf(dg, 1e-20f)) : 0.f;
}
// SYSTEM-scope loads bypass L1 AND the per-XCD L2 -> always fresh, and
// concurrent readers of one line are served in parallel (no RMW serialization).
__device__ __forceinline__ float sysload(const float* p) {
    return __hip_atomic_load(p, __ATOMIC_RELAXED, __HIP_MEMORY_SCOPE_SYSTEM);
}
__device__ __forceinline__ unsigned sysloadu(const unsigned* p) {
    return __hip_atomic_load(p, __ATOMIC_RELAXED, __HIP_MEMORY_SCOPE_SYSTEM);
}
__device__ __forceinline__ void sysstore(float* p, float v) {
    __hip_atomic_store(p, v, __ATOMIC_RELAXED, __HIP_MEMORY_SCOPE_SYSTEM);
}

// Scan 1: collect in-neighbors of node 0; zero deg.
__global__ void k_nbr(const int* __restrict__ ei, const float* __restrict__ ew,
                      float* deg, int* nbrCnt, int* nbrNode, float* nbrW) {
    int gid = blockIdx.x * blockDim.x + threadIdx.x;
    if (gid < NN) deg[gid] = 0.f;
    int e0 = gid * 4;
    if (e0 >= NE) return;
    int4 d4 = *(const int4*)&ei[NE + e0];
    float4 w4 = *(const float4*)&ew[e0];
    int dd[4] = {d4.x, d4.y, d4.z, d4.w};
    float wv[4] = {w4.x, w4.y, w4.z, w4.w};
    #pragma unroll
    for (int k = 0; k < 4; ++k) {
        if (dd[k] == 0 && wv[k] != 0.f) {
            int s = ei[e0 + k];
            if (s != 0) {
                int slot = atomicAdd(nbrCnt, 1);
                if (slot < NBR_CAP) { nbrNode[slot] = s; nbrW[slot] = wv[k]; }
            }
        }
    }
}

// Scan 2: match edges with d==0 or d in nbr(0); record (s,d,w); mark needed nodes.
__global__ void k_match(const int* __restrict__ ei, const float* __restrict__ ew,
                        const int* __restrict__ nbrCnt, const int* __restrict__ nbrNode,
                        int* mCnt, int* mS, int* mD, float* mW, unsigned* bitmap) {
    __shared__ int sNode[NBR_CAP];
    __shared__ int sCnt;
    if (threadIdx.x == 0) sCnt = min(*nbrCnt, NBR_CAP);
    __syncthreads();
    int cnt = sCnt;
    for (int i = threadIdx.x; i < cnt; i += blockDim.x) sNode[i] = nbrNode[i];
    __syncthreads();
    if (blockIdx.x == 0 && threadIdx.x == 0) atomicOr(&bitmap[0], 1u);

    int i = blockIdx.x * blockDim.x + threadIdx.x;
    int e0 = i * 4;
    if (e0 >= NE) return;
    int4 s4 = *(const int4*)&ei[e0];
    int4 d4 = *(const int4*)&ei[NE + e0];
    float4 w4 = *(const float4*)&ew[e0];
    int ss[4] = {s4.x, s4.y, s4.z, s4.w};
    int dd[4] = {d4.x, d4.y, d4.z, d4.w};
    float wv[4] = {w4.x, w4.y, w4.z, w4.w};
    bool m[4];
    #pragma unroll
    for (int k = 0; k < 4; ++k) m[k] = (dd[k] == 0);
    for (int j = 0; j < cnt; ++j) {
        int nv = sNode[j];
        #pragma unroll
        for (int k = 0; k < 4; ++k) m[k] |= (dd[k] == nv);
    }
    #pragma unroll
    for (int k = 0; k < 4; ++k) {
        int s = ss[k], d = dd[k];
        float w = wv[k];
        if (s == d || w == 0.f || !m[k]) continue;
        int slot = atomicAdd(mCnt, 1);
        if (slot < M_CAP) { mS[slot] = s; mD[slot] = d; mW[slot] = w; }
        atomicOr(&bitmap[s >> 5], 1u << (s & 31));
        atomicOr(&bitmap[d >> 5], 1u << (d & 31));
    }
}

// Scan 3: deg[s] += w only for bitmap-marked srcs.
__global__ void k_deg(const int* __restrict__ ei, const float* __restrict__ ew,
                      const unsigned* __restrict__ bitmap, float* deg) {
    int i = blockIdx.x * blockDim.x + threadIdx.x;
    int e0 = i * 4;
    if (e0 >= NE) return;
    int4 s4 = *(const int4*)&ei[e0];
    int4 d4 = *(const int4*)&ei[NE + e0];
    float4 w4 = *(const float4*)&ew[e0];
    int ss[4] = {s4.x, s4.y, s4.z, s4.w};
    int dd[4] = {d4.x, d4.y, d4.z, d4.w};
    float wv[4] = {w4.x, w4.y, w4.z, w4.w};
    #pragma unroll
    for (int k = 0; k < 4; ++k) {
        int s = ss[k];
        if (s == dd[k] || wv[k] == 0.f) continue;
        if (bitmap[s >> 5] & (1u << (s & 31)))
            atomicAdd(&deg[s], wv[k]);
    }
}

// Tail: block-local T-slice -> gemv -> (1 barrier) -> gates -> 7 flag-synced steps.
// 32 blocks x 256 threads. Block b: T/theta p-slice [b*36,b*36+36), gate rows
// {g*256 + b*8 + k} in VGPRs, h-outputs [b*8, b*8+8).
__global__ __launch_bounds__(TTHR) void k_tail(
    const float* __restrict__ x, const float* __restrict__ h, const float* __restrict__ c,
    const float* __restrict__ theta_x, const float* __restrict__ bias_x,
    const float* __restrict__ theta_h, const float* __restrict__ bias_h,
    const float* __restrict__ w_c, const float* __restrict__ b_gate,
    const float* __restrict__ w_ih, const float* __restrict__ w_hh,
    const float* __restrict__ b_ih, const float* __restrict__ b_hh,
    const float* __restrict__ w_out, const float* __restrict__ b_out,
    float* __restrict__ out, char* __restrict__ ws) {

    float*    deg    = (float*)(ws + O_DEG);
    int*      nbrCnt = (int*)(ws + O_NBRCNT);
    int*      mCnt   = (int*)(ws + O_MCNT);
    unsigned* done   = (unsigned*)(ws + O_DONE);
    unsigned* flags  = (unsigned*)(ws + O_FLAGS);
    float*    gacc   = (float*)(ws + O_GACC);
    float*    hglob  = (float*)(ws + O_HGLOB);
    int*      nbrNode= (int*)(ws + O_NBRNODE);
    float*    nbrW   = (float*)(ws + O_NBRW);
    int*      mS     = (int*)(ws + O_MS);
    int*      mD     = (int*)(ws + O_MD);
    float*    mW     = (float*)(ws + O_MW);

    __shared__ int   sNode[NBR_CAP];
    __shared__ float sWl[NBR_CAP];
    __shared__ float cf1[ECHUNK], cf2[ECHUNK];
    __shared__ float tp1[7][PSLICE], tp2[7][PSLICE];
    __shared__ float tslice[PSLICE];
    __shared__ float sh[HDIM], sc[HDIM];
    __shared__ float sdot[32];
    __shared__ float swsum[4];
    __shared__ int   sCnt, sMcnt;

    const int tid = threadIdx.x, bid = blockIdx.x;

    // ---- w_hh rows into VGPRs (32 floats/thread) ----
    const int rl = tid >> 3, seg = tid & 7;
    const int grow = (rl >> 3) * HDIM + bid * 8 + (rl & 7);
    float4 wreg[8];
    #pragma unroll
    for (int k = 0; k < 8; ++k)
        wreg[k] = *(const float4*)&w_hh[(size_t)grow * HDIM + seg * 32 + k * 4];
    const float wih_r = w_ih[grow];
    const float br    = b_ih[grow] + b_hh[grow];
    const float bo    = b_out[0];
    const float wout_r = w_out[tid];

    if (tid == 0) { sCnt = min(*nbrCnt, NBR_CAP); sMcnt = min(*mCnt, M_CAP); }
    __syncthreads();
    const int ncnt = sCnt, mcnt = sMcnt;
    for (int i = tid; i < ncnt; i += TTHR) { sNode[i] = nbrNode[i]; sWl[i] = nbrW[i]; }
    __syncthreads();

    // ---- phase A: block-local T-slice (no cross-block accum, no barrier) ----
    const float dis0 = dis_of(deg[0]);
    const int pl = tid % PSLICE, gr = tid / PSLICE;       // 7 edge-groups x 36 p's
    const int p = bid * PSLICE + pl;
    const bool isx = p < 3 * FD;
    const int q = isx ? p : p - 3 * FD;
    const int korder = isx ? (q / FD) : (q / HDIM);
    const int f = isx ? (q % FD) : (q % HDIM);
    const float* fbase = isx ? (x + f) : (h + f);
    const int fstride = isx ? FD : HDIM;
    const float f0 = fbase[0];                            // node-0 value

    float a1 = 0.f, a2 = 0.f;
    for (int c0i = 0; c0i < mcnt; c0i += ECHUNK) {
        int clen = min(ECHUNK, mcnt - c0i);
        for (int i = tid; i < clen; i += TTHR) {          // per-edge coefs (parallel)
            int sI = mS[c0i + i], dI = mD[c0i + i];
            float w = mW[c0i + i];
            float disd = dis_of(deg[dI]);
            float wn = dis_of(deg[sI]) * w * disd;
            float Wd = 0.f;
            for (int j = 0; j < ncnt; ++j) Wd += (sNode[j] == dI) ? sWl[j] : 0.f;
            cf1[i] = (dI == 0) ? wn : 0.f;
            cf2[i] = wn * (dis0 * disd * Wd);
        }
        __syncthreads();
        if (gr < 7) {
            for (int i = gr; i < clen; i += 7) {
                float v = fbase[(size_t)mS[c0i + i] * fstride];
                a1 += cf1[i] * v;
                a2 += cf2[i] * v;
            }
        }
        __syncthreads();
    }
    if (gr < 7) { tp1[gr][pl] = a1; tp2[gr][pl] = a2; }
    __syncthreads();
    if (tid < PSLICE) {
        float A1 = 0.f, A2 = 0.f;
        #pragma unroll
        for (int g2 = 0; g2 < 7; ++g2) { A1 += tp1[g2][tid]; A2 += tp2[g2][tid]; }
        tslice[tid] = (korder == 0) ? f0 : ((korder == 1) ? -A1 : 2.f * A2 - f0);
    }
    __syncthreads();

    // ---- phase B: gemv over this block's p-slice; thread owns output o=tid ----
    {
        const int o = tid;
        float g0 = 0.f, g1 = 0.f, g2v = 0.f, g3 = 0.f;
        #pragma unroll 4
        for (int pp = 0; pp < PSLICE; ++pp) {
            int p2 = bid * PSLICE + pp;
            float tv = tslice[pp];
            bool ix = p2 < 3 * FD;
            int qq = ix ? p2 : p2 - 3 * FD;
            const float* b = ix ? (theta_x + (size_t)qq * HDIM)
                                : (theta_h + (size_t)qq * HDIM);
            size_t gs = ix ? (size_t)(3 * FD) * HDIM : (size_t)(3 * HDIM) * HDIM;
            g0  += tv * b[o];
            g1  += tv * b[gs + o];
            g2v += tv * b[2 * gs + o];
            g3  += tv * b[3 * gs + o];
        }
        atomicAdd(&gacc[0 * HDIM + o], g0);
        atomicAdd(&gacc[1 * HDIM + o], g1);
        atomicAdd(&gacc[2 * HDIM + o], g2v);
        atomicAdd(&gacc[3 * HDIM + o], g3);
    }
    // one barrier: syncthreads drains every wave's atomics (vmcnt0), then 1
    // release-arrival per block; poll via system-scope LOAD (no RMW contention).
    __syncthreads();
    if (tid == 0) {
        __hip_atomic_fetch_add(done, 1u, __ATOMIC_RELEASE, __HIP_MEMORY_SCOPE_AGENT);
        while (sysloadu(done) < TAILB) __builtin_amdgcn_s_sleep(1);
    }
    __syncthreads();

    // ---- phase C: gates (redundant per block), h0/c0 into LDS ----
    {
        const int o = tid;
        float g0 = sysload(&gacc[0 * HDIM + o]) + bias_x[0 * HDIM + o] + bias_h[0 * HDIM + o];
        float g1 = sysload(&gacc[1 * HDIM + o]) + bias_x[1 * HDIM + o] + bias_h[1 * HDIM + o];
        float g2 = sysload(&gacc[2 * HDIM + o]) + bias_x[2 * HDIM + o] + bias_h[2 * HDIM + o];
        float g3 = sysload(&gacc[3 * HDIM + o]) + bias_x[3 * HDIM + o] + bias_h[3 * HDIM + o];
        float c0 = c[o];
        float I  = sigm(g0 + w_c[0 * HDIM + o] * c0 + b_gate[0 * HDIM + o]);
        float Fg = sigm(g1 + w_c[1 * HDIM + o] * c0 + b_gate[1 * HDIM + o]);
        float Cn = Fg * c0 + I * tanhf(g2 + b_gate[2 * HDIM + o]);
        float O  = sigm(g3 + w_c[2 * HDIM + o] * Cn + b_gate[3 * HDIM + o]);
        sh[o] = O * tanhf(Cn);
        sc[o] = Cn;
    }
    __syncthreads();
    float creg = (tid < 8) ? sc[bid * 8 + tid] : 0.f;
    float sinp = x[FD - 1];

    // ---- phase D: 7 LSTM steps, flag-signaled (no barriers, no hot line) ----
    for (int t = 0; t < TT; ++t) {
        float acc = 0.f;
        #pragma unroll
        for (int k = 0; k < 8; ++k) {
            float4 hv = *(const float4*)&sh[seg * 32 + k * 4];
            acc += hv.x * wreg[k].x + hv.y * wreg[k].y + hv.z * wreg[k].z + hv.w * wreg[k].w;
        }
        acc += __shfl_down(acc, 4);
        acc += __shfl_down(acc, 2);
        acc += __shfl_down(acc, 1);
        if (seg == 0) sdot[rl] = acc + sinp * wih_r + br;
        __syncthreads();
        if (tid < 8) {
            float iv = sdot[tid], fv = sdot[8 + tid], gv = sdot[16 + tid], ov = sdot[24 + tid];
            float cn = sigm(fv) * creg + sigm(iv) * tanhf(gv);
            float hn = sigm(ov) * tanhf(cn);
            creg = cn;
            sysstore(&hglob[t * HDIM + bid * 8 + tid], hn);
        }
        if (tid == 0)   // same wave as the h stores -> release orders them
            __hip_atomic_store(&flags[t * 32 + bid], 1u, __ATOMIC_RELEASE,
                               __HIP_MEMORY_SCOPE_SYSTEM);
        while (sysloadu(&flags[t * 32 + (tid & 31)]) == 0u)
            __builtin_amdgcn_s_sleep(1);
        float hv2 = sysload(&hglob[t * HDIM + tid]);
        sh[tid] = hv2;
        float pw = wout_r * hv2;
        pw += __shfl_down(pw, 32);
        pw += __shfl_down(pw, 16);
        pw += __shfl_down(pw, 8);
        pw += __shfl_down(pw, 4);
        pw += __shfl_down(pw, 2);
        pw += __shfl_down(pw, 1);
        if ((tid & 63) == 0) swsum[tid >> 6] = pw;
        __syncthreads();
        float sval = swsum[0] + swsum[1] + swsum[2] + swsum[3] + bo;
        if (bid == 0 && tid == 0) out[t] = sval;
        sinp = sval;
    }
}

extern "C" void kernel_launch(void* const* d_in, const int* in_sizes, int n_in,
                              void* d_out, int out_size, void* d_ws, size_t ws_size,
                              hipStream_t stream) {
    const float* x       = (const float*)d_in[0];
    const int*   ei      = (const int*)d_in[1];
    const float* ew      = (const float*)d_in[2];
    const float* h       = (const float*)d_in[3];
    const float* c       = (const float*)d_in[4];
    const float* theta_x = (const float*)d_in[5];
    const float* bias_x  = (const float*)d_in[6];
    const float* theta_h = (const float*)d_in[7];
    const float* bias_h  = (const float*)d_in[8];
    const float* w_c     = (const float*)d_in[9];
    const float* b_gate  = (const float*)d_in[10];
    const float* w_ih    = (const float*)d_in[11];
    const float* w_hh    = (const float*)d_in[12];
    const float* b_ih    = (const float*)d_in[13];
    const float* b_hh    = (const float*)d_in[14];
    const float* w_out   = (const float*)d_in[15];
    const float* b_out   = (const float*)d_in[16];
    char* ws = (char*)d_ws;

    float*    deg    = (float*)(ws + O_DEG);
    unsigned* bitmap = (unsigned*)(ws + O_BITMAP);
    int*      nbrCnt = (int*)(ws + O_NBRCNT);
    int*      mCnt   = (int*)(ws + O_MCNT);
    int*      nbrNode= (int*)(ws + O_NBRNODE);
    float*    nbrW   = (float*)(ws + O_NBRW);
    int*      mS     = (int*)(ws + O_MS);
    int*      mD     = (int*)(ws + O_MD);
    float*    mW     = (float*)(ws + O_MW);

    hipMemsetAsync(ws + CTRL_OFF, 0, CTRL_BYTES, stream);

    int eb4 = (NE / 4 + 255) / 256;
    k_nbr<<<eb4, 256, 0, stream>>>(ei, ew, deg, nbrCnt, nbrNode, nbrW);
    k_match<<<eb4, 256, 0, stream>>>(ei, ew, nbrCnt, nbrNode, mCnt, mS, mD, mW, bitmap);
    k_deg<<<eb4, 256, 0, stream>>>(ei, ew, bitmap, deg);
    k_tail<<<TAILB, TTHR, 0, stream>>>(x, h, c, theta_x, bias_x, theta_h, bias_h,
                                       w_c, b_gate, w_ih, w_hh, b_ih, b_hh, w_out, b_out,
                                       (float*)d_out, ws);
}